// Round 15
// baseline (29.148 us; speedup 1.0000x reference)
//
#include <hip/hip_runtime.h>
#include <hip/hip_fp16.h>

// Problem constants (fixed by the reference):
//   B=64, L=2048, D=1024, seq f32, begin/end int32 (harness downcasts int64),
//   out f32 [B, D]
#define B_ 64
#define L_ 2048
#define D_ 1024
#define D4 (D_ / 4)   // 256 float4 per row
#define CG 32         // column groups: 8 float4 = 128B stripe
#define RS 8          // row slices per span (R15: was 4; tail-shave lever, 3rd step)
// R12/R14 structure (best: 28.1us @ RS=4). Block (gc, b), gc=g*8+r, owns
// batch b, column group g (128B stripe), row eighth r. Streams len/8 rows x
// 128B, LDS-reduces to 8 float4, flushes ONE 64B f16 partial. ws = 1 MB.
// Grid (256,64) = 16384 blocks = 8x oversubscription (quantum <= 16 KB).
// No atomics, no fences (R8: per-block device fences = 330us disaster).
// R13 lesson: stage2 grid must be 256 blocks x 256 thr = 65536 outputs.

__global__ __launch_bounds__(256) void seg_mean_stage1(
    const float* __restrict__ seq,
    const int* __restrict__ begin,
    const int* __restrict__ end,
    __half* __restrict__ ws)
{
    const int gc = blockIdx.x;        // 0..255
    const int g  = gc >> 3;           // column group 0..31
    const int r  = gc & 7;            // row eighth 0..7
    const int b  = blockIdx.y;

    const int bg  = begin[b];
    const int en  = end[b];
    const int len = en - bg;          // >= 1 (len*8 <= 8184 fits int)
    const int l0  = bg + ((len * r) >> 3);
    const int l1  = bg + ((len * (r + 1)) >> 3);   // eighths tile [bg, en)

    const int col8   = threadIdx.x & 7;    // f4 col within group
    const int rowoff = threadIdx.x >> 3;   // 0..31

    // f4 address of row l: b*L*256 + l*256 + g*8 + col8
    const float4* __restrict__ base =
        reinterpret_cast<const float4*>(seq) + (size_t)b * (L_ * D4) + g * 8 + col8;

    float4 a0 = make_float4(0.f, 0.f, 0.f, 0.f);
    float4 a1 = a0, a2 = a0, a3 = a0;

    int l = l0 + rowoff;
    for (; l < l1 - 96; l += 128) {        // 4 independent 16B loads in flight
        float4 v0 = base[(size_t)(l +  0) * D4];
        float4 v1 = base[(size_t)(l + 32) * D4];
        float4 v2 = base[(size_t)(l + 64) * D4];
        float4 v3 = base[(size_t)(l + 96) * D4];
        a0.x += v0.x; a0.y += v0.y; a0.z += v0.z; a0.w += v0.w;
        a1.x += v1.x; a1.y += v1.y; a1.z += v1.z; a1.w += v1.w;
        a2.x += v2.x; a2.y += v2.y; a2.z += v2.z; a2.w += v2.w;
        a3.x += v3.x; a3.y += v3.y; a3.z += v3.z; a3.w += v3.w;
    }
    for (; l < l1; l += 32) {
        float4 v = base[(size_t)l * D4];
        a0.x += v.x; a0.y += v.y; a0.z += v.z; a0.w += v.w;
    }

    float4 acc;
    acc.x = (a0.x + a1.x) + (a2.x + a3.x);
    acc.y = (a0.y + a1.y) + (a2.y + a3.y);
    acc.z = (a0.z + a1.z) + (a2.z + a3.z);
    acc.w = (a0.w + a1.w) + (a2.w + a3.w);

    // Reduce the 32 row-slots per column (bit pattern t&7 preserved).
    __shared__ float4 red[256];
    red[threadIdx.x] = acc;
    __syncthreads();
    #pragma unroll
    for (int s = 128; s >= 8; s >>= 1) {
        if (threadIdx.x < s) {
            float4 o = red[threadIdx.x + s];
            red[threadIdx.x].x += o.x;
            red[threadIdx.x].y += o.y;
            red[threadIdx.x].z += o.z;
            red[threadIdx.x].w += o.w;
        }
        __syncthreads();
    }

    if (threadIdx.x < 8) {
        float4 t = red[threadIdx.x];
        const float inv = 1.0f / (float)len;   // pre-scale: stage2 is a plain add
        union { __half2 h2[2]; float2 f2; } u;
        u.h2[0] = __floats2half2_rn(t.x * inv, t.y * inv);
        u.h2[1] = __floats2half2_rn(t.z * inv, t.w * inv);
        // slot = (b*CG + g)*RS + r ; 32 halfs (64B) per slot
        float2* __restrict__ w2 = reinterpret_cast<float2*>(ws);
        w2[(size_t)(((b * CG + g) * RS + r)) * 8 + threadIdx.x] = u.f2;
    }
}

// Stage 2: 256 blocks x 256 threads; one output float per thread.
// out[b][col] = sum_{r=0..7} ws[b][g][r][c]  (f16 -> f32).
__global__ __launch_bounds__(256) void seg_mean_stage2(
    const __half* __restrict__ ws,
    float* __restrict__ out)
{
    const int idx = blockIdx.x * 256 + threadIdx.x;   // 0..65535
    const int b   = idx >> 10;
    const int col = idx & 1023;
    const int g   = col >> 5;
    const int c   = col & 31;

    const size_t s0 = (size_t)((b * CG + g) * RS) * 32 + c;
    float acc = 0.f;
    #pragma unroll
    for (int r = 0; r < RS; ++r)
        acc += __half2float(ws[s0 + (size_t)r * 32]);
    out[idx] = acc;
}

extern "C" void kernel_launch(void* const* d_in, const int* in_sizes, int n_in,
                              void* d_out, int out_size, void* d_ws, size_t ws_size,
                              hipStream_t stream) {
    const float* seq   = (const float*)d_in[0];
    const int*   begin = (const int*)d_in[1];   // int32: harness downcasts jnp.int64
    const int*   end   = (const int*)d_in[2];
    float*       out   = (float*)d_out;
    __half*      ws    = (__half*)d_ws;         // 64*32*8*32 halfs = 1 MB

    dim3 g1(CG * RS, B_);                       // gc fastest -> de-alias batch->CU
    seg_mean_stage1<<<g1, 256, 0, stream>>>(seq, begin, end, ws);
    seg_mean_stage2<<<256, 256, 0, stream>>>(ws, out);   // 65536 outputs
}

// Round 16
// 27.278 us; speedup vs baseline: 1.0686x; 1.0686x over previous
//
#include <hip/hip_runtime.h>
#include <hip/hip_fp16.h>

// Problem constants (fixed by the reference):
//   B=64, L=2048, D=1024, seq f32, begin/end int32 (harness downcasts int64),
//   out f32 [B, D]
#define B_ 64
#define L_ 2048
#define D_ 1024
#define D4 (D_ / 4)   // 256 float4 per row
#define CG 16         // column groups: 16 float4 = 256B stripe (R16: was 32/128B)
#define RS 8          // row slices per span
// Single-variable test vs R14 (CG=32,RS=4, 28.1us): SAME 8192 blocks, SAME
// <=32KB quantum, but 256B stripes -> half as many interleaved per-row DRAM
// streams (row-buffer locality). Block (gc,b), gc=g*8+r: batch b, column
// group g (16 f4), row eighth r. 256 thr = 16 cols x 16 row-slots.
// LDS-reduce to 16 f4, flush ONE 128B f16 partial; ws = 1 MB.
// No atomics, no fences (R8: per-block device fences = 330us disaster).
// R13 lesson: stage2 = 256 blocks x 256 thr = 65536 outputs, literal grid.

__global__ __launch_bounds__(256) void seg_mean_stage1(
    const float* __restrict__ seq,
    const int* __restrict__ begin,
    const int* __restrict__ end,
    __half* __restrict__ ws)
{
    const int gc = blockIdx.x;        // 0..127
    const int g  = gc >> 3;           // column group 0..15
    const int r  = gc & 7;            // row eighth 0..7
    const int b  = blockIdx.y;

    const int bg  = begin[b];
    const int en  = end[b];
    const int len = en - bg;          // >= 1 (len*8 fits int easily)
    const int l0  = bg + ((len * r) >> 3);
    const int l1  = bg + ((len * (r + 1)) >> 3);   // eighths tile [bg, en)

    const int col16  = threadIdx.x & 15;   // f4 col within 256B stripe
    const int rowoff = threadIdx.x >> 4;   // 0..15

    // f4 address of row l: b*L*256 + l*256 + g*16 + col16
    const float4* __restrict__ base =
        reinterpret_cast<const float4*>(seq) + (size_t)b * (L_ * D4) + g * 16 + col16;

    float4 a0 = make_float4(0.f, 0.f, 0.f, 0.f);
    float4 a1 = a0, a2 = a0, a3 = a0;

    int l = l0 + rowoff;
    for (; l < l1 - 48; l += 64) {         // 4 independent 16B loads in flight
        float4 v0 = base[(size_t)(l +  0) * D4];
        float4 v1 = base[(size_t)(l + 16) * D4];
        float4 v2 = base[(size_t)(l + 32) * D4];
        float4 v3 = base[(size_t)(l + 48) * D4];
        a0.x += v0.x; a0.y += v0.y; a0.z += v0.z; a0.w += v0.w;
        a1.x += v1.x; a1.y += v1.y; a1.z += v1.z; a1.w += v1.w;
        a2.x += v2.x; a2.y += v2.y; a2.z += v2.z; a2.w += v2.w;
        a3.x += v3.x; a3.y += v3.y; a3.z += v3.z; a3.w += v3.w;
    }
    for (; l < l1; l += 16) {
        float4 v = base[(size_t)l * D4];
        a0.x += v.x; a0.y += v.y; a0.z += v.z; a0.w += v.w;
    }

    float4 acc;
    acc.x = (a0.x + a1.x) + (a2.x + a3.x);
    acc.y = (a0.y + a1.y) + (a2.y + a3.y);
    acc.z = (a0.z + a1.z) + (a2.z + a3.z);
    acc.w = (a0.w + a1.w) + (a2.w + a3.w);

    // Reduce the 16 row-slots per column (t&15 preserved by strides >= 16).
    __shared__ float4 red[256];
    red[threadIdx.x] = acc;
    __syncthreads();
    #pragma unroll
    for (int s = 128; s >= 16; s >>= 1) {
        if (threadIdx.x < s) {
            float4 o = red[threadIdx.x + s];
            red[threadIdx.x].x += o.x;
            red[threadIdx.x].y += o.y;
            red[threadIdx.x].z += o.z;
            red[threadIdx.x].w += o.w;
        }
        __syncthreads();
    }

    if (threadIdx.x < 16) {
        float4 t = red[threadIdx.x];
        const float inv = 1.0f / (float)len;   // pre-scale: stage2 is a plain add
        union { __half2 h2[2]; float2 f2; } u;
        u.h2[0] = __floats2half2_rn(t.x * inv, t.y * inv);
        u.h2[1] = __floats2half2_rn(t.z * inv, t.w * inv);
        // slot = (b*CG + g)*RS + r ; 64 halfs (128B) per slot; half index
        // within slot = t*4..t*4+3 -> float col g*64 + halfidx.
        float2* __restrict__ w2 = reinterpret_cast<float2*>(ws);
        w2[(size_t)(((b * CG + g) * RS + r)) * 16 + threadIdx.x] = u.f2;
    }
}

// Stage 2: 256 blocks x 256 threads; one output float per thread.
// out[b][col] = sum_{r=0..7} ws_slot(b, g=col>>6, r)[col&63]  (f16 -> f32).
__global__ __launch_bounds__(256) void seg_mean_stage2(
    const __half* __restrict__ ws,
    float* __restrict__ out)
{
    const int idx = blockIdx.x * 256 + threadIdx.x;   // 0..65535
    const int b   = idx >> 10;
    const int col = idx & 1023;
    const int g   = col >> 6;
    const int c   = col & 63;

    const size_t s0 = (size_t)((b * CG + g) * RS) * 64 + c;
    float acc = 0.f;
    #pragma unroll
    for (int r = 0; r < RS; ++r)
        acc += __half2float(ws[s0 + (size_t)r * 64]);
    out[idx] = acc;
}

extern "C" void kernel_launch(void* const* d_in, const int* in_sizes, int n_in,
                              void* d_out, int out_size, void* d_ws, size_t ws_size,
                              hipStream_t stream) {
    const float* seq   = (const float*)d_in[0];
    const int*   begin = (const int*)d_in[1];   // int32: harness downcasts jnp.int64
    const int*   end   = (const int*)d_in[2];
    float*       out   = (float*)d_out;
    __half*      ws    = (__half*)d_ws;         // 64*16*8*64 halfs = 1 MB

    dim3 g1(CG * RS, B_);                       // gc fastest -> de-alias batch->CU
    seg_mean_stage1<<<g1, 256, 0, stream>>>(seq, begin, end, ws);
    seg_mean_stage2<<<256, 256, 0, stream>>>(ws, out);   // 65536 outputs
}